// Round 16
// baseline (36.424 us; speedup 1.0000x reference)
//
#include <hip/hip_runtime.h>

// Problem constants (from reference setup_inputs)
#define BB 4
#define CC 128
#define HH 256
#define WW 256
#define NKP 4096
#define INV_RATIO (1.0f / 16.0f)
#define CPT 4                 // channels per group
#define NXCD 8
#define JBLK 32               // blocks per group (kp-chunks)
#define CHUNK 128             // keypoints per tile
#define TILES 4               // tiles per block

typedef float fpair __attribute__((ext_vector_type(2)));
typedef const __attribute__((address_space(1))) void gvoid;
typedef __attribute__((address_space(3))) void svoid;

// Grid: 1024 blocks x 256. Block (xcd=bid&7, s=bid>>3): cohort c=s>>5,
// j=s&31. Tile t: gloc=c*4+t, group g=gloc*8+xcd (bijective over 128
// groups x 32 j-chunks x ... = 4096 tiles). Each tile: 128 kp x 4 ch.
//
// Prefetch: each block streams its 32KB slice (j of 1MB group) via
// global_load_lds dwordx4 into a dump LDS buffer (never read). The 32
// sibling blocks of a group are co-resident on one XCD -> the group's
// 1MB enters HBM as sequential requests; the random gathers hit L2 or
// merge with in-flight sequential fetches. Per-XCD concurrent footprint
// ~4 groups = 4MB = L2 size.
//
// Determinism: outputs are pure functions of inputs, each (b,c,n)
// written exactly once; dump LDS is write-only garbage.
__global__ __launch_bounds__(256) void interp_pf_kernel(
    const float* __restrict__ feature,     // B x C x H x W
    const float* __restrict__ keypoints,   // B x N x 2
    float* __restrict__ out)               // B x C x N
{
    __shared__ float dump[4][256];         // 4KB: per-wave 1KB dump target

    int bid  = blockIdx.x;                 // 0..1023
    int xcd  = bid & (NXCD - 1);
    int s    = bid >> 3;                   // 0..127
    int c    = s >> 5;                     // cohort 0..3
    int j    = s & 31;                     // kp-chunk 0..31
    int tid  = threadIdx.x;
    int w    = tid >> 6, lane = tid & 63;

    int kpi  = tid & (CHUNK - 1);          // 0..127
    int ch2  = (tid >> 7) & 1;             // channel-pair 0/1

    for (int t = 0; t < TILES; ++t) {
        int gloc = c * TILES + t;          // 0..15
        int g    = gloc * NXCD + xcd;      // 0..127
        int b    = g >> 5;
        int c0   = (g & 31) * CPT;

        const float* fg = feature + (size_t)(b * CC + c0) * (HH * WW);

        // ---- sequential prefetch of this block's 32KB slice ----
        const char* pbase = (const char*)fg
                          + ((size_t)j << 15) + ((size_t)w << 13) + ((size_t)lane << 4);
        svoid* ldst = (svoid*)&dump[w][0];
        #pragma unroll
        for (int r = 0; r < 8; ++r) {
            __builtin_amdgcn_global_load_lds((gvoid*)(pbase + (r << 10)), ldst, 16, 0, 0);
        }

        // ---- gather (R8 math) for kp n, channels c0+2*ch2, +1 ----
        int n = j * CHUNK + kpi;
        const float* kp = keypoints + ((size_t)(b * NKP + n)) * 2;
        float kx = kp[0] * INV_RATIO;
        float ky = kp[1] * INV_RATIO;

        float fx = fmaxf(floorf(kx), 0.0f);
        float fy = fmaxf(floorf(ky), 0.0f);
        int x0 = (int)fx, y0 = (int)fy;

        float ux = kx - fx, uy = ky - fy;
        float lx = 1.0f - ux, ly = 1.0f - uy;

        bool selx = (x0 >= WW - 1);
        bool sely = (y0 >= HH - 1);
        int xp = selx ? (WW - 2) : x0;
        int yp = sely ? (HH - 2) : y0;
        float wlx = selx ? 0.0f : lx, wux = selx ? 1.0f : ux;
        float wly = sely ? 0.0f : ly, wuy = sely ? 1.0f : uy;

        float mask = 0.5f * ((kx > 1e-10f ? 1.0f : 0.0f) + (ky > 1e-10f ? 1.0f : 0.0f));
        float w00 = wlx * wly * mask, w01 = wux * wly * mask;
        float w10 = wlx * wuy * mask, w11 = wux * wuy * mask;

        int i0 = yp * WW + xp;
        int i1 = i0 + WW;

        const float* fc = fg + (size_t)(2 * ch2) * (HH * WW);
        fpair a0, a1, b0, b1;
        __builtin_memcpy(&a0, fc + i0, sizeof(fpair));
        __builtin_memcpy(&a1, fc + i1, sizeof(fpair));
        __builtin_memcpy(&b0, fc + (HH * WW) + i0, sizeof(fpair));
        __builtin_memcpy(&b1, fc + (HH * WW) + i1, sizeof(fpair));

        float v0 = w00 * a0.x + w01 * a0.y + w10 * a1.x + w11 * a1.y;
        float v1 = w00 * b0.x + w01 * b0.y + w10 * b1.x + w11 * b1.y;

        float* o = out + (size_t)(b * CC + c0 + 2 * ch2) * NKP + n;
        __builtin_nontemporal_store(v0, o);
        __builtin_nontemporal_store(v1, o + NKP);
    }
}

extern "C" void kernel_launch(void* const* d_in, const int* in_sizes, int n_in,
                              void* d_out, int out_size, void* d_ws, size_t ws_size,
                              hipStream_t stream) {
    const float* feature   = (const float*)d_in[0];
    const float* keypoints = (const float*)d_in[1];
    float* out = (float*)d_out;

    interp_pf_kernel<<<1024, 256, 0, stream>>>(feature, keypoints, out);
}

// Round 17
// 30.385 us; speedup vs baseline: 1.1987x; 1.1987x over previous
//
#include <hip/hip_runtime.h>

// Problem constants (from reference setup_inputs)
#define BB 4
#define CC 128
#define HH 256
#define WW 256
#define NKP 4096
#define INV_RATIO (1.0f / 16.0f)
#define CPT 4                 // channels per thread
#define NXCD 8

typedef float fpair __attribute__((ext_vector_type(2)));

// Grid: BB * (CC/CPT) * (NKP/256) = 2048 blocks of 256 threads.
// Swizzle: map-group g (= b*32 + c0/CPT) pinned to XCD g%8 (128 groups,
// 128%8==0 -> bijective). Each 4-map group (1 MB) is fetched into exactly
// one L2; keypoint line-reuse served from L2.
//
// Per (kp, channel) the two x-corners of each row are fetched with ONE
// 8-byte load (memcpy -> global_load_dwordx2, 4B-aligned OK on gfx950):
// 8.4M -> 4.2M scattered transactions vs the scalar version. Row-pair
// start clamped to W-2; the x0==W-1 (kx==255.0) case is folded into the
// x-weights (wlx=0, wux=1 -> picks pair.y with total weight lx+ux=1).
//
// ROOFLINE NOTE (R0-R16 campaign): 30.2-30.4 us, triply reproduced.
// The binding constraint is the ~4.4M compulsory scattered 64B
// line-requests (~268 MB through the L3->L2->L1 request path at the
// observed random-line service rate), NOT HBM BW (fills run 7.1 TB/s;
// R13's streaming variant showed FETCH=66MB @ 12% peak while slower) and
// NOT instruction issue (R7/R11 flat or worse on instruction cuts).
// Probed and rejected: line-sorted gather (R10, +8us overhead), transposed
// mapping (R11, -7%), LDS band-streaming scan/lists (R13/R14, +5-15us),
// sequential prefetch-warming via global_load_lds (R16, +6us). Each
// alternative pays more than the request path it relieves; the line-touch
// volume itself is compulsory to bilinear gather at 128 channels.
__global__ __launch_bounds__(256) void interp_kernel(
    const float* __restrict__ feature,     // B x C x H x W
    const float* __restrict__ keypoints,   // B x N x 2
    float* __restrict__ out)               // B x C x N
{
    int bid   = blockIdx.x;        // 0..2047
    int xcd   = bid & (NXCD - 1);
    int slot  = bid >> 3;          // 0..255
    int gloc  = slot >> 4;         // 0..15
    int j     = slot & 15;         // 0..15
    int g     = gloc * NXCD + xcd; // 0..127
    int b     = g >> 5;
    int c0    = (g & 31) * CPT;
    int n     = j * 256 + threadIdx.x;

    const float* kp = keypoints + ((size_t)(b * NKP + n)) * 2;
    float kx = kp[0] * INV_RATIO;
    float ky = kp[1] * INV_RATIO;

    float fx = fmaxf(floorf(kx), 0.0f);
    float fy = fmaxf(floorf(ky), 0.0f);
    int x0 = (int)fx, y0 = (int)fy;

    float ux = kx - fx, uy = ky - fy;
    float lx = 1.0f - ux, ly = 1.0f - uy;

    // clamp pair start; fold boundary select into weights (once per kp)
    bool selx = (x0 >= WW - 1);
    bool sely = (y0 >= HH - 1);
    int xp = selx ? (WW - 2) : x0;
    int yp = sely ? (HH - 2) : y0;
    float wlx = selx ? 0.0f : lx, wux = selx ? 1.0f : ux;
    float wly = sely ? 0.0f : ly, wuy = sely ? 1.0f : uy;

    // mask folded into the 4 weights
    float mask = 0.5f * ((kx > 1e-10f ? 1.0f : 0.0f) + (ky > 1e-10f ? 1.0f : 0.0f));
    float w00 = wlx * wly * mask, w01 = wux * wly * mask;
    float w10 = wlx * wuy * mask, w11 = wux * wuy * mask;

    int i0 = yp * WW + xp;         // row y-lo pair
    int i1 = i0 + WW;              // row y-hi pair

    const float* f = feature + ((size_t)(b * CC + c0)) * (HH * WW);

    fpair r0[CPT], r1[CPT];
    #pragma unroll
    for (int k = 0; k < CPT; ++k) {
        const float* fc = f + (size_t)k * (HH * WW);
        __builtin_memcpy(&r0[k], fc + i0, sizeof(fpair));
        __builtin_memcpy(&r1[k], fc + i1, sizeof(fpair));
    }

    float* o = out + ((size_t)(b * CC + c0)) * NKP + n;
    #pragma unroll
    for (int k = 0; k < CPT; ++k) {
        float val = w00 * r0[k].x + w01 * r0[k].y
                  + w10 * r1[k].x + w11 * r1[k].y;
        __builtin_nontemporal_store(val, o + (size_t)k * NKP);
    }
}

extern "C" void kernel_launch(void* const* d_in, const int* in_sizes, int n_in,
                              void* d_out, int out_size, void* d_ws, size_t ws_size,
                              hipStream_t stream) {
    const float* feature   = (const float*)d_in[0];
    const float* keypoints = (const float*)d_in[1];
    float* out = (float*)d_out;

    const int grid = BB * (CC / CPT) * (NKP / 256);  // 2048
    interp_kernel<<<grid, 256, 0, stream>>>(feature, keypoints, out);
}